// Round 4
// baseline (1156.913 us; speedup 1.0000x reference)
//
#include <hip/hip_runtime.h>
#include <hip/hip_bf16.h>

typedef unsigned short u16;
typedef unsigned int u32;

typedef __attribute__((ext_vector_type(8))) short bf16x8;
typedef __attribute__((ext_vector_type(4))) float f32x4;

__device__ __forceinline__ u16 f2bf(float f) {
    u32 u = __float_as_uint(f);
    u32 r = ((u >> 16) & 1u) + 0x7fffu;
    return (u16)((u + r) >> 16);
}
__device__ __forceinline__ float bf2f(u16 u) {
    return __uint_as_float(((u32)u) << 16);
}
// order-preserving float<->uint for atomicMax-based segment max
__device__ __forceinline__ u32 f2ord(float f) {
    u32 u = __float_as_uint(f);
    return (u & 0x80000000u) ? ~u : (u | 0x80000000u);
}
__device__ __forceinline__ float ord2f(u32 u) {
    return (u & 0x80000000u) ? __uint_as_float(u & 0x7fffffffu)
                             : __uint_as_float(~u);
}
__device__ __forceinline__ float leaky(float x) { return x >= 0.f ? x : 0.01f * x; }

// ---------------------------------------------------------------- prep:
// transpose W_edge[128,128], W_msg[128,128] (f32) -> bf16 [n][k]
__global__ __launch_bounds__(256) void k_prep_transpose(
    const float* __restrict__ We, const float* __restrict__ Wm,
    u16* __restrict__ WeT, u16* __restrict__ WmT)
{
    int idx = blockIdx.x * 256 + threadIdx.x;   // grid=128 -> 0..32767
    int m = idx >> 14;
    int r = (idx >> 7) & 127;
    int c = idx & 127;
    const float* S = m ? Wm : We;
    u16* D = m ? WmT : WeT;
    D[c * 128 + r] = f2bf(S[r * 128 + c]);
}

// ---------------------------------------------------------------- (1) node embed
// h_v = leaky(nf @ W_node + b_node)  [N,128] f32, 8 nodes/block, f32 VALU
__global__ __launch_bounds__(128) void k_node_embed(
    const float* __restrict__ nf, const float* __restrict__ Wn,
    const float* __restrict__ bn, float* __restrict__ h_v, int nN)
{
    __shared__ float sW[64][128];
    __shared__ float sF[8][64];
    int j = threadIdx.x;
    int n0 = blockIdx.x * 8;
    for (int i = 0; i < 64; i++) sW[i][j] = Wn[i * 128 + j];
    for (int t = j; t < 8 * 64; t += 128) {
        int n = t >> 6, k = t & 63;
        int nn = n0 + n; if (nn >= nN) nn = nN - 1;
        sF[n][k] = nf[(long)nn * 64 + k];
    }
    __syncthreads();
    float bj = bn[j];
    for (int n = 0; n < 8; n++) {
        if (n0 + n >= nN) break;
        float acc = bj;
        #pragma unroll 16
        for (int k = 0; k < 64; k++) acc += sF[n][k] * sW[k][j];
        h_v[(long)(n0 + n) * 128 + j] = leaky(acc);
    }
}

// stage e_in = [nf[src] | ef] (f32 -> bf16) into sIn[64][136]
__device__ __forceinline__ void stage_ein(
    u16 (*sIn)[136], const float* nf, const float* ef,
    const int* sSrc, long e0, int nE, int tid)
{
    for (int c = tid; c < 64 * 32; c += 256) {   // 32 float4-chunks per edge
        int e = c >> 5, p = c & 31;
        long eg = e0 + e; if (eg >= nE) eg = nE - 1;
        float4 v;
        if (p < 16) v = *((const float4*)(nf + (long)sSrc[e] * 64 + p * 4));
        else        v = *((const float4*)(ef + eg * 64 + (p - 16) * 4));
        u32 lo = (u32)f2bf(v.x) | ((u32)f2bf(v.y) << 16);
        u32 hi = (u32)f2bf(v.z) | ((u32)f2bf(v.w) << 16);
        *((u32*)&sIn[e][p * 4])     = lo;
        *((u32*)&sIn[e][p * 4 + 2]) = hi;
    }
}

// ---------------------------------------------------------------- (2+3) fused
// edge embed (MFMA, LDS-only) + attention logit + segment max. 64 edges/block.
__global__ __launch_bounds__(256) void k_edge_logit(
    const float* __restrict__ nf, const float* __restrict__ ef,
    const int* __restrict__ src, const int* __restrict__ dst,
    const u16* __restrict__ WeT, const float* __restrict__ be,
    const float* __restrict__ WL, const float* __restrict__ bL,
    const float* __restrict__ h_v,
    float* __restrict__ logit, u32* __restrict__ lmax, int nE)
{
    __shared__ u16 sIn[64][136];
    __shared__ u16 sW[128][136];
    __shared__ u16 sHe[64][136];
    __shared__ float sWL[256];
    __shared__ int sSrc[64];
    int tid = threadIdx.x;
    long e0 = (long)blockIdx.x * 64;
    if (tid < 64) {
        long eg = e0 + tid; if (eg >= nE) eg = nE - 1;
        sSrc[tid] = src[eg];
    }
    sWL[tid] = WL[tid];
    __syncthreads();
    for (int c = tid; c < 2048; c += 256) {      // W_edge^T bf16, 16B chunks
        int r = c >> 4, p = c & 15;
        *((uint4*)&sW[r][p * 8]) = *((const uint4*)(WeT + r * 128 + p * 8));
    }
    stage_ein(sIn, nf, ef, sSrc, e0, nE, tid);
    __syncthreads();

    int lane = tid & 63, w = tid >> 6;
    int nl = lane & 15, q = lane >> 4;
    f32x4 acc[8];
    #pragma unroll
    for (int t = 0; t < 8; t++) acc[t] = (f32x4){0.f, 0.f, 0.f, 0.f};
    int eA = w * 16 + nl;                        // A row = lane&15
    #pragma unroll
    for (int s = 0; s < 4; s++) {
        int k0 = s * 32 + q * 8;                 // A/B k = quad*8 + j
        bf16x8 a = *((const bf16x8*)&sIn[eA][k0]);
        #pragma unroll
        for (int t = 0; t < 8; t++) {
            bf16x8 b = *((const bf16x8*)&sW[t * 16 + nl][k0]);
            acc[t] = __builtin_amdgcn_mfma_f32_16x16x32_bf16(a, b, acc[t], 0, 0, 0);
        }
    }
    // C/D: row = quad*4 + reg, col = lane&15
    #pragma unroll
    for (int t = 0; t < 8; t++) {
        int col = t * 16 + nl;
        float bias = be[col];
        #pragma unroll
        for (int r = 0; r < 4; r++) {
            int e = w * 16 + q * 4 + r;
            sHe[e][col] = f2bf(leaky(acc[t][r] + bias));
        }
    }
    __syncthreads();

    int e = tid >> 2;
    int sub = tid & 3;
    float sum = 0.f;
    if (sub < 2) {
        int s = sSrc[e];
        const float4* hv = (const float4*)(h_v + (long)s * 128 + sub * 64);
        #pragma unroll
        for (int i = 0; i < 16; i++) {
            float4 v = hv[i];
            int c = sub * 64 + i * 4;
            sum += v.x * sWL[c] + v.y * sWL[c + 1] + v.z * sWL[c + 2] + v.w * sWL[c + 3];
        }
    } else {
        #pragma unroll
        for (int i = 0; i < 16; i++) {
            int c0 = (sub - 2) * 64 + i * 4;
            sum += bf2f(sHe[e][c0])     * sWL[128 + c0]
                 + bf2f(sHe[e][c0 + 1]) * sWL[128 + c0 + 1]
                 + bf2f(sHe[e][c0 + 2]) * sWL[128 + c0 + 2]
                 + bf2f(sHe[e][c0 + 3]) * sWL[128 + c0 + 3];
        }
    }
    sum += __shfl_xor(sum, 1);
    sum += __shfl_xor(sum, 2);
    if (sub == 0 && e0 + e < nE) {
        float l = leaky(sum + bL[0]);
        logit[e0 + e] = l;
        atomicMax(&lmax[dst[e0 + e]], f2ord(l));
    }
}

// ---------------------------------------------------------------- (4) exp + denom
__global__ __launch_bounds__(256) void k_softmax_den(
    const int* __restrict__ dst, float* __restrict__ logit_ex,
    const u32* __restrict__ lmax, float* __restrict__ den, int nE)
{
    long e = (long)blockIdx.x * 256 + threadIdx.x;
    if (e >= nE) return;
    int d = dst[e];
    float ex = __expf(logit_ex[e] - ord2f(lmax[d]));
    logit_ex[e] = ex;
    atomicAdd(&den[d], ex);
}

// ---------------------------------------------------------------- (5) msg + scatter
// recompute h_e (MFMA #1), m = h_e @ W_msg (MFMA #2), Cacc[dst] += alpha*m
__global__ __launch_bounds__(256) void k_msg_scatter(
    const float* __restrict__ nf, const float* __restrict__ ef,
    const int* __restrict__ src, const int* __restrict__ dst,
    const u16* __restrict__ WeT, const float* __restrict__ be,
    const u16* __restrict__ WmT, const float* __restrict__ bm,
    const float* __restrict__ ex, const float* __restrict__ den,
    float* __restrict__ Cacc, int nE)
{
    __shared__ u16 sIn[64][136];
    __shared__ u16 sW[128][136];    // W_edge^T, then reused for W_msg^T
    __shared__ u16 sHe[64][136];
    __shared__ float sAlpha[64];
    __shared__ int sSrc[64];
    __shared__ int sDst[64];
    int tid = threadIdx.x;
    long e0 = (long)blockIdx.x * 64;
    if (tid < 64) {
        long eg = e0 + tid; if (eg >= nE) eg = nE - 1;
        sSrc[tid] = src[eg];
    } else if (tid < 128) {
        int t = tid - 64;
        long eg = e0 + t;
        if (eg < nE) {
            int d = dst[eg];
            sDst[t] = d;
            sAlpha[t] = ex[eg] / den[d];
        } else { sDst[t] = 0; sAlpha[t] = 0.f; }
    }
    __syncthreads();
    for (int c = tid; c < 2048; c += 256) {
        int r = c >> 4, p = c & 15;
        *((uint4*)&sW[r][p * 8]) = *((const uint4*)(WeT + r * 128 + p * 8));
    }
    stage_ein(sIn, nf, ef, sSrc, e0, nE, tid);
    __syncthreads();

    int lane = tid & 63, w = tid >> 6;
    int nl = lane & 15, q = lane >> 4;
    int eA = w * 16 + nl;
    f32x4 acc[8];
    #pragma unroll
    for (int t = 0; t < 8; t++) acc[t] = (f32x4){0.f, 0.f, 0.f, 0.f};
    #pragma unroll
    for (int s = 0; s < 4; s++) {
        int k0 = s * 32 + q * 8;
        bf16x8 a = *((const bf16x8*)&sIn[eA][k0]);
        #pragma unroll
        for (int t = 0; t < 8; t++) {
            bf16x8 b = *((const bf16x8*)&sW[t * 16 + nl][k0]);
            acc[t] = __builtin_amdgcn_mfma_f32_16x16x32_bf16(a, b, acc[t], 0, 0, 0);
        }
    }
    #pragma unroll
    for (int t = 0; t < 8; t++) {
        int col = t * 16 + nl;
        float bias = be[col];
        #pragma unroll
        for (int r = 0; r < 4; r++) {
            int e = w * 16 + q * 4 + r;
            sHe[e][col] = f2bf(leaky(acc[t][r] + bias));
        }
    }
    __syncthreads();                 // all waves done with W_edge^T + sHe written
    for (int c = tid; c < 2048; c += 256) {
        int r = c >> 4, p = c & 15;
        *((uint4*)&sW[r][p * 8]) = *((const uint4*)(WmT + r * 128 + p * 8));
    }
    __syncthreads();

    #pragma unroll
    for (int t = 0; t < 8; t++) acc[t] = (f32x4){0.f, 0.f, 0.f, 0.f};
    #pragma unroll
    for (int s = 0; s < 4; s++) {
        int k0 = s * 32 + q * 8;
        bf16x8 a = *((const bf16x8*)&sHe[eA][k0]);
        #pragma unroll
        for (int t = 0; t < 8; t++) {
            bf16x8 b = *((const bf16x8*)&sW[t * 16 + nl][k0]);
            acc[t] = __builtin_amdgcn_mfma_f32_16x16x32_bf16(a, b, acc[t], 0, 0, 0);
        }
    }
    #pragma unroll
    for (int t = 0; t < 8; t++) {
        int col = t * 16 + nl;
        float bias = bm[col];
        #pragma unroll
        for (int r = 0; r < 4; r++) {
            int el = w * 16 + q * 4 + r;
            if (e0 + el < nE) {
                float m = acc[t][r] + bias;
                atomicAdd(&Cacc[(long)sDst[el] * 128 + col], sAlpha[el] * m);
            }
        }
    }
}

// ---------------------------------------------------------------- (6) GRU
__global__ __launch_bounds__(128) void k_gru(
    const float* __restrict__ h_v, const float* __restrict__ Cacc,
    const float* __restrict__ Wih, const float* __restrict__ Whh,
    const float* __restrict__ bih, const float* __restrict__ bhh,
    float* __restrict__ out, int nN)
{
    __shared__ float sC[8][128];
    __shared__ float sH[8][128];
    int j = threadIdx.x;
    int n0 = blockIdx.x * 8;
    for (int n = 0; n < 8; n++) {
        int nn = n0 + n; if (nn >= nN) nn = nN - 1;
        float c = Cacc[(long)nn * 128 + j];
        sC[n][j] = c > 0.f ? c : (__expf(c) - 1.f);   // elu
        sH[n][j] = h_v[(long)nn * 128 + j];
    }
    __syncthreads();
    float gi[3][8], gh[3][8];
    #pragma unroll
    for (int g = 0; g < 3; g++) {
        float bi = bih[g * 128 + j];
        float bh = bhh[g * 128 + j];
        #pragma unroll
        for (int n = 0; n < 8; n++) { gi[g][n] = bi; gh[g][n] = bh; }
    }
    for (int k = 0; k < 128; k += 4) {
        float4 cv[8], hv[8];
        #pragma unroll
        for (int n = 0; n < 8; n++) {
            cv[n] = *(const float4*)&sC[n][k];
            hv[n] = *(const float4*)&sH[n][k];
        }
        #pragma unroll
        for (int g = 0; g < 3; g++) {
            float4 wi = *((const float4*)(Wih + (long)(g * 128 + j) * 128 + k));
            float4 wh = *((const float4*)(Whh + (long)(g * 128 + j) * 128 + k));
            #pragma unroll
            for (int n = 0; n < 8; n++) {
                gi[g][n] += wi.x * cv[n].x + wi.y * cv[n].y + wi.z * cv[n].z + wi.w * cv[n].w;
                gh[g][n] += wh.x * hv[n].x + wh.y * hv[n].y + wh.z * hv[n].z + wh.w * hv[n].w;
            }
        }
    }
    #pragma unroll
    for (int n = 0; n < 8; n++) {
        if (n0 + n >= nN) break;
        float r = 1.f / (1.f + __expf(-(gi[0][n] + gh[0][n])));
        float z = 1.f / (1.f + __expf(-(gi[1][n] + gh[1][n])));
        float nn = tanhf(gi[2][n] + r * gh[2][n]);
        float h = (1.f - z) * nn + z * sH[n][j];
        out[(long)(n0 + n) * 128 + j] = (h > 0.f ? h : 0.f);
    }
}

extern "C" void kernel_launch(void* const* d_in, const int* in_sizes, int n_in,
                              void* d_out, int out_size, void* d_ws, size_t ws_size,
                              hipStream_t stream) {
    // All float tensors are FLOAT32 per the reference (jnp.float32).
    const float* nf  = (const float*)d_in[0];
    const float* ef  = (const float*)d_in[1];
    const float* Wn  = (const float*)d_in[2];
    const float* bn  = (const float*)d_in[3];
    const float* We  = (const float*)d_in[4];
    const float* be  = (const float*)d_in[5];
    const float* WL  = (const float*)d_in[6];
    const float* bL  = (const float*)d_in[7];
    const float* Wm  = (const float*)d_in[8];
    const float* bm  = (const float*)d_in[9];
    const float* Wih = (const float*)d_in[10];
    const float* Whh = (const float*)d_in[11];
    const float* bih = (const float*)d_in[12];
    const float* bhh = (const float*)d_in[13];
    const int* src = (const int*)d_in[14];
    const int* dst = (const int*)d_in[15];
    float* out = (float*)d_out;

    int nN = in_sizes[0] / 64;        // node count (NF=64)
    int nE = in_sizes[1] / 64;        // edge count (EF=64)

    char* w = (char*)d_ws;
    float* h_v   = (float*)w;  w += (size_t)nN * 128 * 4;
    float* logit = (float*)w;  w += (size_t)nE * 4;
    u32*   lmax  = (u32*)w;    w += ((size_t)nN + 256) * 4;
    float* den   = (float*)w;  w += ((size_t)nN + 256) * 4;
    float* Cacc  = (float*)w;  w += (size_t)nN * 128 * 4;
    u16*   WeT   = (u16*)w;    w += 128 * 128 * 2;
    u16*   WmT   = (u16*)w;    w += 128 * 128 * 2;

    // zero lmax + den + Cacc in one shot (contiguous)
    size_t zbytes = ((size_t)nN + 256) * 4 * 2 + (size_t)nN * 128 * 4;
    hipMemsetAsync(lmax, 0, zbytes, stream);

    int gN8   = (nN + 7) / 8;
    int gE64  = (nE + 63) / 64;
    int gE256 = (nE + 255) / 256;

    k_prep_transpose<<<128, 256, 0, stream>>>(We, Wm, WeT, WmT);
    k_node_embed<<<gN8, 128, 0, stream>>>(nf, Wn, bn, h_v, nN);
    k_edge_logit<<<gE64, 256, 0, stream>>>(nf, ef, src, dst, WeT, be,
                                           WL, bL, h_v, logit, lmax, nE);
    k_softmax_den<<<gE256, 256, 0, stream>>>(dst, logit, lmax, den, nE);
    k_msg_scatter<<<gE64, 256, 0, stream>>>(nf, ef, src, dst, WeT, be,
                                            WmT, bm, logit, den, Cacc, nE);
    k_gru<<<gN8, 128, 0, stream>>>(h_v, Cacc, Wih, Whh, bih, bhh, out, nN);

    // passthrough edge_feats (f32) -> second output
    hipMemcpyAsync(out + (size_t)nN * 128, ef, (size_t)nE * 64 * 4,
                   hipMemcpyDeviceToDevice, stream);
}